// Round 1
// baseline (355.985 us; speedup 1.0000x reference)
//
#include <hip/hip_runtime.h>
#include <math.h>

// Problem constants (match reference)
#define N_NODES 50000
#define N_EDGES 800000
#define DFEAT   128
#define MAXNORM (1.0f - 4e-3f)   // (1 - BALL_EPS)/sqrt(c), c=1

// -------------------- kernels --------------------

// deg[i] = 1 (the appended self-loop)
__global__ void k_init_deg(int* __restrict__ deg, int n) {
    int i = blockIdx.x * blockDim.x + threadIdx.x;
    if (i < n) deg[i] = 1;
}

// deg[row] += 1 for every non-self edge
__global__ void k_hist(const int* __restrict__ row, const int* __restrict__ col,
                       int* __restrict__ deg, int e) {
    int i = blockIdx.x * blockDim.x + threadIdx.x;
    if (i < e) {
        int r = row[i], c = col[i];
        if (r != c) atomicAdd(&deg[r], 1);
    }
}

// Single-block exclusive scan of cnt[i] = deg[i]-1 -> offs, cursor(=offs copy)
__global__ __launch_bounds__(1024) void k_scan(const int* __restrict__ deg,
                                               int* __restrict__ offs,
                                               int* __restrict__ cursor, int n) {
    __shared__ int sums[1024];
    int t = threadIdx.x;
    int chunk = (n + 1023) / 1024;
    int start = t * chunk;
    int end   = min(start + chunk, n);
    int s = 0;
    for (int i = start; i < end; ++i) s += deg[i] - 1;
    sums[t] = s;
    __syncthreads();
    // Hillis-Steele inclusive scan in LDS
    for (int off = 1; off < 1024; off <<= 1) {
        int v = 0;
        if (t >= off) v = sums[t - off];
        __syncthreads();
        if (t >= off) sums[t] += v;
        __syncthreads();
    }
    int run = (t == 0) ? 0 : sums[t - 1];
    for (int i = start; i < end; ++i) {
        offs[i]   = run;
        cursor[i] = run;
        run += deg[i] - 1;
    }
    if (t == 1023) offs[n] = run;
}

// adj[cursor[row]++] = col for every non-self edge
__global__ void k_scatter(const int* __restrict__ row, const int* __restrict__ col,
                          int* __restrict__ cursor, int* __restrict__ adj, int e) {
    int i = blockIdx.x * blockDim.x + threadIdx.x;
    if (i < e) {
        int r = row[i], c = col[i];
        if (r != c) {
            int pos = atomicAdd(&cursor[r], 1);
            adj[pos] = c;
        }
    }
}

// One wave (64 lanes) per destination row; each lane owns 2 floats (float2).
__global__ __launch_bounds__(256) void k_gather(const float* __restrict__ x,
                                                const int* __restrict__ adj,
                                                const int* __restrict__ offs,
                                                const int* __restrict__ deg,
                                                float* __restrict__ out, int n) {
    int wave_in_blk = threadIdx.x >> 6;           // 0..3
    int lane        = threadIdx.x & 63;
    int rowi        = blockIdx.x * 4 + wave_in_blk;
    if (rowi >= n) return;

    const float2* __restrict__ x2 = (const float2*)x;
    int beg = offs[rowi];
    int cnt = deg[rowi] - 1;

    float2 acc = make_float2(0.0f, 0.0f);
    for (int nb = 0; nb < cnt; ++nb) {
        int c = adj[beg + nb];                    // wave-uniform -> L1 broadcast
        float w = rsqrtf((float)deg[c]);          // dis[col]
        float2 v = x2[c * (DFEAT / 2) + lane];    // coalesced 512B per wave
        acc.x += w * v.x;
        acc.y += w * v.y;
    }
    float di = rsqrtf((float)deg[rowi]);          // dis[row]
    float2 self = x2[rowi * (DFEAT / 2) + lane];
    // result = di * (sum + di * self)
    acc.x = di * (acc.x + di * self.x);
    acc.y = di * (acc.y + di * self.y);

    // 64-lane norm^2 reduction
    float nsq = acc.x * acc.x + acc.y * acc.y;
    #pragma unroll
    for (int off = 32; off > 0; off >>= 1) nsq += __shfl_xor(nsq, off);

    float un = fmaxf(sqrtf(nsq), 1e-15f);
    float th = tanhf(un);
    float scale = th / un;                        // expmap0 scaling
    if (th > MAXNORM) scale *= MAXNORM / th;      // proj clamp (||p|| == tanh(un))

    float2 o = make_float2(acc.x * scale, acc.y * scale);
    ((float2*)out)[rowi * (DFEAT / 2) + lane] = o;
}

// -------------------- launcher --------------------

extern "C" void kernel_launch(void* const* d_in, const int* in_sizes, int n_in,
                              void* d_out, int out_size, void* d_ws, size_t ws_size,
                              hipStream_t stream) {
    const float* x          = (const float*)d_in[0];
    const int*   edge_index = (const int*)d_in[1];
    const int*   row = edge_index;            // [E]
    const int*   col = edge_index + N_EDGES;  // [E]
    float* out = (float*)d_out;

    // workspace layout (ints)
    char* ws = (char*)d_ws;
    int* deg    = (int*)ws;                                   // N
    int* offs   = (int*)(ws + sizeof(int) * (size_t)N_NODES);             // N+1
    int* cursor = (int*)(ws + sizeof(int) * (size_t)(2 * N_NODES + 1));   // N
    int* adj    = (int*)(ws + sizeof(int) * (size_t)(3 * N_NODES + 1));   // E

    dim3 blk(256);
    k_init_deg<<<dim3((N_NODES + 255) / 256), blk, 0, stream>>>(deg, N_NODES);
    k_hist<<<dim3((N_EDGES + 255) / 256), blk, 0, stream>>>(row, col, deg, N_EDGES);
    k_scan<<<dim3(1), dim3(1024), 0, stream>>>(deg, offs, cursor, N_NODES);
    k_scatter<<<dim3((N_EDGES + 255) / 256), blk, 0, stream>>>(row, col, cursor, adj, N_EDGES);
    k_gather<<<dim3((N_NODES + 3) / 4), blk, 0, stream>>>(x, adj, offs, deg, out, N_NODES);
}

// Round 2
// 233.665 us; speedup vs baseline: 1.5235x; 1.5235x over previous
//
#include <hip/hip_runtime.h>
#include <math.h>

// Problem constants (match reference)
#define N_NODES 50000
#define N_EDGES 800000
#define DFEAT   128
#define MAXNORM (1.0f - 4e-3f)   // (1 - BALL_EPS)/sqrt(c), c=1

#define SCAN_BLK 256
#define NUM_SCAN_BLOCKS ((N_NODES + SCAN_BLK - 1) / SCAN_BLK)   // 196

// -------------------- kernels --------------------

// deg[i] = 1 (the appended self-loop)
__global__ void k_init_deg(int* __restrict__ deg, int n) {
    int i = blockIdx.x * blockDim.x + threadIdx.x;
    if (i < n) deg[i] = 1;
}

// deg[row] += 1 for every non-self edge
__global__ void k_hist(const int* __restrict__ row, const int* __restrict__ col,
                       int* __restrict__ deg, int e) {
    int i = blockIdx.x * blockDim.x + threadIdx.x;
    if (i < e) {
        int r = row[i], c = col[i];
        if (r != c) atomicAdd(&deg[r], 1);
    }
}

// Pass A: per-block sum of cnt[i] = deg[i]-1
__global__ __launch_bounds__(SCAN_BLK) void k_block_sums(const int* __restrict__ deg,
                                                         int* __restrict__ blockSums, int n) {
    __shared__ int s[SCAN_BLK];
    int t = threadIdx.x;
    int i = blockIdx.x * SCAN_BLK + t;
    s[t] = (i < n) ? (deg[i] - 1) : 0;
    __syncthreads();
    for (int off = SCAN_BLK / 2; off > 0; off >>= 1) {
        if (t < off) s[t] += s[t + off];
        __syncthreads();
    }
    if (t == 0) blockSums[blockIdx.x] = s[0];
}

// Pass B: single-block exclusive scan of blockSums[NUM_SCAN_BLOCKS] -> blockBase
__global__ __launch_bounds__(SCAN_BLK) void k_scan_blocks(const int* __restrict__ blockSums,
                                                          int* __restrict__ blockBase) {
    __shared__ int s[SCAN_BLK];
    int t = threadIdx.x;
    s[t] = (t < NUM_SCAN_BLOCKS) ? blockSums[t] : 0;
    __syncthreads();
    for (int off = 1; off < SCAN_BLK; off <<= 1) {
        int v = (t >= off) ? s[t - off] : 0;
        __syncthreads();
        s[t] += v;
        __syncthreads();
    }
    if (t < NUM_SCAN_BLOCKS) blockBase[t] = (t == 0) ? 0 : s[t - 1];
}

// Pass C: block-local exclusive scan + base -> offs, cursor; also dis = rsqrt(deg)
__global__ __launch_bounds__(SCAN_BLK) void k_block_scan(const int* __restrict__ deg,
                                                         const int* __restrict__ blockBase,
                                                         int* __restrict__ offs,
                                                         int* __restrict__ cursor,
                                                         float* __restrict__ dis, int n) {
    __shared__ int s[SCAN_BLK];
    int t = threadIdx.x;
    int i = blockIdx.x * SCAN_BLK + t;
    int cnt = (i < n) ? (deg[i] - 1) : 0;
    s[t] = cnt;
    __syncthreads();
    for (int off = 1; off < SCAN_BLK; off <<= 1) {
        int v = (t >= off) ? s[t - off] : 0;
        __syncthreads();
        s[t] += v;
        __syncthreads();
    }
    if (i < n) {
        int excl = s[t] - cnt + blockBase[blockIdx.x];
        offs[i]   = excl;
        cursor[i] = excl;
        dis[i]    = rsqrtf((float)deg[i]);
    }
}

// adj[cursor[row]++] = col for every non-self edge
__global__ void k_scatter(const int* __restrict__ row, const int* __restrict__ col,
                          int* __restrict__ cursor, int* __restrict__ adj, int e) {
    int i = blockIdx.x * blockDim.x + threadIdx.x;
    if (i < e) {
        int r = row[i], c = col[i];
        if (r != c) {
            int pos = atomicAdd(&cursor[r], 1);
            adj[pos] = c;
        }
    }
}

// One wave (64 lanes) per destination row; each lane owns 2 floats (float2).
__global__ __launch_bounds__(256) void k_gather(const float* __restrict__ x,
                                                const int* __restrict__ adj,
                                                const int* __restrict__ offs,
                                                const int* __restrict__ deg,
                                                const float* __restrict__ dis,
                                                float* __restrict__ out, int n) {
    int wave_in_blk = threadIdx.x >> 6;           // 0..3
    int lane        = threadIdx.x & 63;
    int rowi        = blockIdx.x * 4 + wave_in_blk;
    if (rowi >= n) return;

    const float2* __restrict__ x2 = (const float2*)x;
    int beg = offs[rowi];
    int cnt = deg[rowi] - 1;

    float2 acc = make_float2(0.0f, 0.0f);
    for (int base = 0; base < cnt; base += 64) {
        int m = cnt - base; if (m > 64) m = 64;
        int a = 0;
        if (lane < m) a = adj[beg + base + lane];  // one coalesced load per 64 nbrs
        for (int nb = 0; nb < m; ++nb) {
            int c = __shfl(a, nb);
            float w = dis[c];
            float2 v = x2[c * (DFEAT / 2) + lane]; // coalesced 512B per wave
            acc.x += w * v.x;
            acc.y += w * v.y;
        }
    }
    float di = dis[rowi];
    float2 self = x2[rowi * (DFEAT / 2) + lane];
    // result = di * (sum + di * self)
    acc.x = di * (acc.x + di * self.x);
    acc.y = di * (acc.y + di * self.y);

    // 64-lane norm^2 reduction
    float nsq = acc.x * acc.x + acc.y * acc.y;
    #pragma unroll
    for (int off = 32; off > 0; off >>= 1) nsq += __shfl_xor(nsq, off);

    float un = fmaxf(sqrtf(nsq), 1e-15f);
    float th = tanhf(un);
    float scale = th / un;                        // expmap0 scaling
    if (th > MAXNORM) scale *= MAXNORM / th;      // proj clamp (||p|| == tanh(un))

    float2 o = make_float2(acc.x * scale, acc.y * scale);
    ((float2*)out)[rowi * (DFEAT / 2) + lane] = o;
}

// -------------------- launcher --------------------

extern "C" void kernel_launch(void* const* d_in, const int* in_sizes, int n_in,
                              void* d_out, int out_size, void* d_ws, size_t ws_size,
                              hipStream_t stream) {
    const float* x          = (const float*)d_in[0];
    const int*   edge_index = (const int*)d_in[1];
    const int*   row = edge_index;            // [E]
    const int*   col = edge_index + N_EDGES;  // [E]
    float* out = (float*)d_out;

    // workspace layout
    char* ws = (char*)d_ws;
    size_t off = 0;
    int*   deg       = (int*)(ws + off); off += sizeof(int) * (size_t)N_NODES;
    int*   offs      = (int*)(ws + off); off += sizeof(int) * (size_t)N_NODES;
    int*   cursor    = (int*)(ws + off); off += sizeof(int) * (size_t)N_NODES;
    float* dis       = (float*)(ws + off); off += sizeof(float) * (size_t)N_NODES;
    int*   blockSums = (int*)(ws + off); off += sizeof(int) * (size_t)NUM_SCAN_BLOCKS;
    int*   blockBase = (int*)(ws + off); off += sizeof(int) * (size_t)NUM_SCAN_BLOCKS;
    int*   adj       = (int*)(ws + off);

    dim3 blk(256);
    k_init_deg<<<dim3((N_NODES + 255) / 256), blk, 0, stream>>>(deg, N_NODES);
    k_hist<<<dim3((N_EDGES + 255) / 256), blk, 0, stream>>>(row, col, deg, N_EDGES);
    k_block_sums<<<dim3(NUM_SCAN_BLOCKS), dim3(SCAN_BLK), 0, stream>>>(deg, blockSums, N_NODES);
    k_scan_blocks<<<dim3(1), dim3(SCAN_BLK), 0, stream>>>(blockSums, blockBase);
    k_block_scan<<<dim3(NUM_SCAN_BLOCKS), dim3(SCAN_BLK), 0, stream>>>(deg, blockBase, offs, cursor, dis, N_NODES);
    k_scatter<<<dim3((N_EDGES + 255) / 256), blk, 0, stream>>>(row, col, cursor, adj, N_EDGES);
    k_gather<<<dim3((N_NODES + 3) / 4), blk, 0, stream>>>(x, adj, offs, deg, dis, out, N_NODES);
}

// Round 5
// 185.256 us; speedup vs baseline: 1.9216x; 1.2613x over previous
//
#include <hip/hip_runtime.h>
#include <math.h>

// Problem constants (match reference)
#define N_NODES 50000
#define N_EDGES 800000
#define DFEAT   128
#define MAXNORM (1.0f - 4e-3f)   // (1 - BALL_EPS)/sqrt(c), c=1
#define CAP     64               // padded adjacency slots per row (deg ~ Poisson(16), max ~45)
#define OVF_CAP 8192

// ==================== padded-adjacency path ====================

__global__ void k_zero(int* __restrict__ deg, int* __restrict__ ovf_cnt, int n) {
    int i = blockIdx.x * blockDim.x + threadIdx.x;
    if (i < n) deg[i] = 0;
    if (i == 0) *ovf_cnt = 0;
}

// one pass over edges: histogram + scatter into padded rows
__global__ void k_build(const int* __restrict__ row, const int* __restrict__ col,
                        int* __restrict__ deg, int* __restrict__ adj,
                        int* __restrict__ ovf, int* __restrict__ ovf_cnt, int e4) {
    int i = blockIdx.x * blockDim.x + threadIdx.x;
    if (i >= e4) return;
    int4 r4 = ((const int4*)row)[i];
    int4 c4 = ((const int4*)col)[i];
    int rs[4] = {r4.x, r4.y, r4.z, r4.w};
    int cs[4] = {c4.x, c4.y, c4.z, c4.w};
    #pragma unroll
    for (int k = 0; k < 4; ++k) {
        int r = rs[k], c = cs[k];
        if (r != c) {
            int pos = atomicAdd(&deg[r], 1);
            if (pos < CAP) adj[r * CAP + pos] = c;
            else {
                int o = atomicAdd(ovf_cnt, 1);
                if (o < OVF_CAP) { ovf[2 * o] = r; ovf[2 * o + 1] = c; }
            }
        }
    }
}

// One wave per destination row; each lane owns 2 floats (float2).
// Structure identical to the round-2-proven CSR gather; only the adjacency
// source (padded rows) and the deg convention (+1 for the self loop) differ.
// NO nontemporal hints (suspected stale-read source on multi-XCD L2).
__global__ __launch_bounds__(256) void k_gather_pad(const float* __restrict__ x,
                                                    const int* __restrict__ adj,
                                                    const int* __restrict__ deg,
                                                    const int* __restrict__ ovf,
                                                    const int* __restrict__ ovf_cnt,
                                                    float* __restrict__ out, int n) {
    int lane = threadIdx.x & 63;
    int rowi = blockIdx.x * 4 + (threadIdx.x >> 6);
    if (rowi >= n) return;

    const float2* __restrict__ x2 = (const float2*)x;
    int cnt    = deg[rowi];
    int capcnt = cnt < CAP ? cnt : CAP;

    int a = 0;
    if (lane < capcnt) a = adj[rowi * CAP + lane];   // one coalesced load per row

    float2 acc = make_float2(0.0f, 0.0f);
    for (int nb = 0; nb < capcnt; ++nb) {
        int c = __shfl(a, nb);
        float w = rsqrtf((float)(deg[c] + 1));       // dis[col]
        float2 v = x2[c * (DFEAT / 2) + lane];       // coalesced 512B per wave
        acc.x += w * v.x;
        acc.y += w * v.y;
    }

    // overflow edges (statistically never non-empty, kept for correctness)
    int novf = *ovf_cnt;
    for (int k = 0; k < novf; ++k) {
        if (ovf[2 * k] == rowi) {
            int c = ovf[2 * k + 1];
            float w = rsqrtf((float)(deg[c] + 1));
            float2 v = x2[c * (DFEAT / 2) + lane];
            acc.x += w * v.x;
            acc.y += w * v.y;
        }
    }

    float di = rsqrtf((float)(cnt + 1));             // dis[row]
    float2 self = x2[rowi * (DFEAT / 2) + lane];
    // result = di * (sum + di * self)
    acc.x = di * (acc.x + di * self.x);
    acc.y = di * (acc.y + di * self.y);

    // 64-lane norm^2 reduction
    float nsq = acc.x * acc.x + acc.y * acc.y;
    #pragma unroll
    for (int off = 32; off > 0; off >>= 1) nsq += __shfl_xor(nsq, off);

    float un = fmaxf(sqrtf(nsq), 1e-15f);
    float th = tanhf(un);
    float scale = th / un;                           // expmap0
    if (th > MAXNORM) scale *= MAXNORM / th;         // proj clamp (||p|| == tanh(un))

    float2 o = make_float2(acc.x * scale, acc.y * scale);
    ((float2*)out)[rowi * (DFEAT / 2) + lane] = o;
}

// ==================== CSR fallback path (proven round-2 code) ====================

#define SCAN_BLK 256
#define NUM_SCAN_BLOCKS ((N_NODES + SCAN_BLK - 1) / SCAN_BLK)

__global__ void k_init_deg(int* __restrict__ deg, int n) {
    int i = blockIdx.x * blockDim.x + threadIdx.x;
    if (i < n) deg[i] = 1;
}

__global__ void k_hist(const int* __restrict__ row, const int* __restrict__ col,
                       int* __restrict__ deg, int e) {
    int i = blockIdx.x * blockDim.x + threadIdx.x;
    if (i < e) {
        int r = row[i], c = col[i];
        if (r != c) atomicAdd(&deg[r], 1);
    }
}

__global__ __launch_bounds__(SCAN_BLK) void k_block_sums(const int* __restrict__ deg,
                                                         int* __restrict__ blockSums, int n) {
    __shared__ int s[SCAN_BLK];
    int t = threadIdx.x;
    int i = blockIdx.x * SCAN_BLK + t;
    s[t] = (i < n) ? (deg[i] - 1) : 0;
    __syncthreads();
    for (int off = SCAN_BLK / 2; off > 0; off >>= 1) {
        if (t < off) s[t] += s[t + off];
        __syncthreads();
    }
    if (t == 0) blockSums[blockIdx.x] = s[0];
}

__global__ __launch_bounds__(SCAN_BLK) void k_scan_blocks(const int* __restrict__ blockSums,
                                                          int* __restrict__ blockBase) {
    __shared__ int s[SCAN_BLK];
    int t = threadIdx.x;
    s[t] = (t < NUM_SCAN_BLOCKS) ? blockSums[t] : 0;
    __syncthreads();
    for (int off = 1; off < SCAN_BLK; off <<= 1) {
        int v = (t >= off) ? s[t - off] : 0;
        __syncthreads();
        s[t] += v;
        __syncthreads();
    }
    if (t < NUM_SCAN_BLOCKS) blockBase[t] = (t == 0) ? 0 : s[t - 1];
}

__global__ __launch_bounds__(SCAN_BLK) void k_block_scan(const int* __restrict__ deg,
                                                         const int* __restrict__ blockBase,
                                                         int* __restrict__ offs,
                                                         int* __restrict__ cursor, int n) {
    __shared__ int s[SCAN_BLK];
    int t = threadIdx.x;
    int i = blockIdx.x * SCAN_BLK + t;
    int cnt = (i < n) ? (deg[i] - 1) : 0;
    s[t] = cnt;
    __syncthreads();
    for (int off = 1; off < SCAN_BLK; off <<= 1) {
        int v = (t >= off) ? s[t - off] : 0;
        __syncthreads();
        s[t] += v;
        __syncthreads();
    }
    if (i < n) {
        int excl = s[t] - cnt + blockBase[blockIdx.x];
        offs[i]   = excl;
        cursor[i] = excl;
    }
}

__global__ void k_scatter(const int* __restrict__ row, const int* __restrict__ col,
                          int* __restrict__ cursor, int* __restrict__ adj, int e) {
    int i = blockIdx.x * blockDim.x + threadIdx.x;
    if (i < e) {
        int r = row[i], c = col[i];
        if (r != c) {
            int pos = atomicAdd(&cursor[r], 1);
            adj[pos] = c;
        }
    }
}

__global__ __launch_bounds__(256) void k_gather_csr(const float* __restrict__ x,
                                                    const int* __restrict__ adj,
                                                    const int* __restrict__ offs,
                                                    const int* __restrict__ deg,
                                                    float* __restrict__ out, int n) {
    int lane = threadIdx.x & 63;
    int rowi = blockIdx.x * 4 + (threadIdx.x >> 6);
    if (rowi >= n) return;

    const float2* __restrict__ x2 = (const float2*)x;
    int beg = offs[rowi];
    int cnt = deg[rowi] - 1;

    float2 acc = make_float2(0.0f, 0.0f);
    for (int base = 0; base < cnt; base += 64) {
        int m = cnt - base; if (m > 64) m = 64;
        int a = 0;
        if (lane < m) a = adj[beg + base + lane];
        for (int nb = 0; nb < m; ++nb) {
            int c = __shfl(a, nb);
            float w = rsqrtf((float)deg[c]);
            float2 v = x2[c * (DFEAT / 2) + lane];
            acc.x += w * v.x;
            acc.y += w * v.y;
        }
    }
    float di = rsqrtf((float)deg[rowi]);
    float2 self = x2[rowi * (DFEAT / 2) + lane];
    acc.x = di * (acc.x + di * self.x);
    acc.y = di * (acc.y + di * self.y);

    float nsq = acc.x * acc.x + acc.y * acc.y;
    #pragma unroll
    for (int off = 32; off > 0; off >>= 1) nsq += __shfl_xor(nsq, off);

    float un = fmaxf(sqrtf(nsq), 1e-15f);
    float th = tanhf(un);
    float scale = th / un;
    if (th > MAXNORM) scale *= MAXNORM / th;

    float2 o = make_float2(acc.x * scale, acc.y * scale);
    ((float2*)out)[rowi * (DFEAT / 2) + lane] = o;
}

// ==================== launcher ====================

extern "C" void kernel_launch(void* const* d_in, const int* in_sizes, int n_in,
                              void* d_out, int out_size, void* d_ws, size_t ws_size,
                              hipStream_t stream) {
    const float* x          = (const float*)d_in[0];
    const int*   edge_index = (const int*)d_in[1];
    const int*   row = edge_index;            // [E]
    const int*   col = edge_index + N_EDGES;  // [E]
    float* out = (float*)d_out;
    char*  ws  = (char*)d_ws;

    // padded-path workspace requirement
    size_t need_pad = sizeof(int) * ((size_t)N_NODES                 // deg
                                     + (size_t)N_NODES * CAP         // adj
                                     + 1                             // ovf_cnt
                                     + 2 * (size_t)OVF_CAP);         // ovf

    dim3 blk(256);
    if (ws_size >= need_pad) {
        size_t off = 0;
        int* deg     = (int*)(ws + off); off += sizeof(int) * (size_t)N_NODES;
        int* adj     = (int*)(ws + off); off += sizeof(int) * (size_t)N_NODES * CAP;
        int* ovf_cnt = (int*)(ws + off); off += sizeof(int);
        int* ovf     = (int*)(ws + off);

        k_zero<<<dim3((N_NODES + 255) / 256), blk, 0, stream>>>(deg, ovf_cnt, N_NODES);
        k_build<<<dim3((N_EDGES / 4 + 255) / 256), blk, 0, stream>>>(row, col, deg, adj, ovf, ovf_cnt, N_EDGES / 4);
        k_gather_pad<<<dim3((N_NODES + 3) / 4), blk, 0, stream>>>(x, adj, deg, ovf, ovf_cnt, out, N_NODES);
    } else {
        size_t off = 0;
        int* deg       = (int*)(ws + off); off += sizeof(int) * (size_t)N_NODES;
        int* offs      = (int*)(ws + off); off += sizeof(int) * (size_t)N_NODES;
        int* cursor    = (int*)(ws + off); off += sizeof(int) * (size_t)N_NODES;
        int* blockSums = (int*)(ws + off); off += sizeof(int) * (size_t)NUM_SCAN_BLOCKS;
        int* blockBase = (int*)(ws + off); off += sizeof(int) * (size_t)NUM_SCAN_BLOCKS;
        int* adj       = (int*)(ws + off);

        k_init_deg<<<dim3((N_NODES + 255) / 256), blk, 0, stream>>>(deg, N_NODES);
        k_hist<<<dim3((N_EDGES + 255) / 256), blk, 0, stream>>>(row, col, deg, N_EDGES);
        k_block_sums<<<dim3(NUM_SCAN_BLOCKS), dim3(SCAN_BLK), 0, stream>>>(deg, blockSums, N_NODES);
        k_scan_blocks<<<dim3(1), dim3(SCAN_BLK), 0, stream>>>(blockSums, blockBase);
        k_block_scan<<<dim3(NUM_SCAN_BLOCKS), dim3(SCAN_BLK), 0, stream>>>(deg, blockBase, offs, cursor, N_NODES);
        k_scatter<<<dim3((N_EDGES + 255) / 256), blk, 0, stream>>>(row, col, cursor, adj, N_EDGES);
        k_gather_csr<<<dim3((N_NODES + 3) / 4), blk, 0, stream>>>(x, adj, offs, deg, out, N_NODES);
    }
}